// Round 1
// baseline (37.310 us; speedup 1.0000x reference)
//
#include <hip/hip_runtime.h>

#define B_TOT 16384
#define F_DIM 512
#define T_DIM 256
#define N_DIM 256
#define NBLK  2048

__device__ __forceinline__ float wave_sum(float v) {
#pragma unroll
    for (int o = 32; o; o >>= 1) v += __shfl_xor(v, o, 64);
    return v;
}
__device__ __forceinline__ float wave_prod(float v) {
#pragma unroll
    for (int o = 32; o; o >>= 1) v *= __shfl_xor(v, o, 64);
    return v;
}

__global__ __launch_bounds__(256, 8) void setcrit_stage1(
    const float* __restrict__ pred_class,
    const float* __restrict__ pred_v,
    const float* __restrict__ targets,
    float* __restrict__ partial)
{
    __shared__ float s_predv[N_DIM];
    __shared__ unsigned char s_mask[T_DIM];
    __shared__ float s_pick[4];
    __shared__ float s_dsq[4];
    __shared__ float s_prod[4];
    __shared__ int   s_cnt[4];

    const int tid  = threadIdx.x;
    const int lane = tid & 63;
    const int wv   = tid >> 6;
    const unsigned long long lt = (1ull << lane) - 1ull;

    float acc_picked = 0.f, acc_multi = 0.f, acc_true = 0.f, acc_f1 = 0.f;

    for (int b = blockIdx.x; b < B_TOT; b += NBLK) {
        // ---- coalesced row loads ----
        float pv = pred_v[(size_t)b * N_DIM + tid];
        s_predv[tid] = pv;
        float tg = targets[(size_t)b * T_DIM + tid];
        // thread tid covers f = 2*tid and 2*tid+1 (float4 = 16B/lane)
        float4 lg = *reinterpret_cast<const float4*>(
            pred_class + (size_t)b * (F_DIM * 2) + (size_t)tid * 4);

        float pick = 0.f;
        {   // f0 = 2*tid
            float l0 = lg.x, l1 = lg.y;
            float m = fmaxf(l0, l1);
            float lse = m + __logf(__expf(l0 - m) + __expf(l1 - m));
            pick += ((2 * tid) < T_DIM ? l1 : l0) - lse;
            if (tid < T_DIM / 2) s_mask[2 * tid] = (unsigned char)(l1 > l0);
        }
        {   // f1 = 2*tid + 1
            float l0 = lg.z, l1 = lg.w;
            float m = fmaxf(l0, l1);
            float lse = m + __logf(__expf(l0 - m) + __expf(l1 - m));
            pick += ((2 * tid + 1) < T_DIM ? l1 : l0) - lse;
            if (tid < T_DIM / 2) s_mask[2 * tid + 1] = (unsigned char)(l1 > l0);
        }
        __syncthreads();

        // ---- mask prefix via ballot/popcount (== cumsum(mask)-1 at masked t) ----
        bool mk = (s_mask[tid] != 0);
        unsigned long long bal = __ballot(mk);
        int wcnt = __popcll(bal);
        if (lane == 0) s_cnt[wv] = wcnt;

        float wp = wave_prod(pv);
        if (lane == 0) s_prod[wv] = wp;
        float wsum = wave_sum(pick);
        if (lane == 0) s_pick[wv] = wsum;
        __syncthreads();

        int off = 0;
        for (int w = 0; w < wv; ++w) off += s_cnt[w];
        int excl = __popcll(bal & lt);
        float dsq = 0.f;
        if (mk) {
            float matched = s_predv[off + excl];
            float d = matched - tg;
            dsq = d * d;
        }
        float wd = wave_sum(dsq);
        if (lane == 0) s_dsq[wv] = wd;
        __syncthreads();

        if (tid == 0) {
            int   tc     = s_cnt[0] + s_cnt[1] + s_cnt[2] + s_cnt[3];
            float prod   = s_prod[0] * s_prod[1] * s_prod[2] * s_prod[3];
            float psum   = s_pick[0] + s_pick[1] + s_pick[2] + s_pick[3];
            float lossv1 = s_dsq[0] + s_dsq[1] + s_dsq[2] + s_dsq[3];
            acc_picked += psum;
            float pm1 = prod - 1.f;
            acc_multi += pm1 * pm1;
            if (tc > 0) {
                acc_true += lossv1 * (1.f / (float)T_DIM);
                acc_f1   += (float)tc * (1.f / (float)T_DIM);
            }
        }
        __syncthreads(); // protect s_* before next iteration
    }

    if (tid == 0) {
        partial[0 * NBLK + blockIdx.x] = acc_picked;
        partial[1 * NBLK + blockIdx.x] = acc_multi;
        partial[2 * NBLK + blockIdx.x] = acc_true;
        partial[3 * NBLK + blockIdx.x] = acc_f1;
    }
}

__global__ __launch_bounds__(256) void setcrit_stage2(
    const float* __restrict__ partial, float* __restrict__ out)
{
    __shared__ float s_red[4];
    const int tid  = threadIdx.x;
    const int lane = tid & 63;
    const int wv   = tid >> 6;
    float sums[4];
#pragma unroll
    for (int k = 0; k < 4; ++k) {
        float v = 0.f;
        for (int i = tid; i < NBLK; i += 256) v += partial[k * NBLK + i];
        v = wave_sum(v);
        if (lane == 0) s_red[wv] = v;
        __syncthreads();
        sums[k] = s_red[0] + s_red[1] + s_red[2] + s_red[3];
        __syncthreads();
    }
    if (tid == 0) {
        float loss_label = -sums[0] / ((float)B_TOT * (float)F_DIM);
        float loss_multi = sums[1] / (float)B_TOT;
        float loss_true  = sums[2] / (float)B_TOT;
        float f1         = sums[3] / (float)B_TOT;
        float r = loss_multi + loss_true;
        out[0] = loss_label + r;
        out[1] = loss_label;
        out[2] = r;
        out[3] = loss_multi;
        out[4] = loss_true;
        out[5] = f1;
    }
}

extern "C" void kernel_launch(void* const* d_in, const int* in_sizes, int n_in,
                              void* d_out, int out_size, void* d_ws, size_t ws_size,
                              hipStream_t stream) {
    const float* pred_class = (const float*)d_in[0];
    const float* pred_v     = (const float*)d_in[1];
    const float* targets    = (const float*)d_in[2];
    float* partial = (float*)d_ws;  // 4 * NBLK floats = 32 KB

    setcrit_stage1<<<NBLK, 256, 0, stream>>>(pred_class, pred_v, targets, partial);
    setcrit_stage2<<<1, 256, 0, stream>>>(partial, (float*)d_out);
}

// Round 2
// 31.916 us; speedup vs baseline: 1.1690x; 1.1690x over previous
//
#include <hip/hip_runtime.h>

#define B_TOT 16384
#define F_DIM 512
#define T_DIM 256
#define N_DIM 256
#define NBLK  2048

__device__ __forceinline__ float wave_sum(float v) {
#pragma unroll
    for (int o = 32; o; o >>= 1) v += __shfl_xor(v, o, 64);
    return v;
}
__device__ __forceinline__ float wave_prod(float v) {
#pragma unroll
    for (int o = 32; o; o >>= 1) v *= __shfl_xor(v, o, 64);
    return v;
}

__device__ __forceinline__ float lse2(float a, float b) {
    float m = fmaxf(a, b);
    return m + __logf(__expf(a - m) + __expf(b - m));
}

// One wave per row. Lane l owns logits f-pairs {2l,2l+1,128+2l,129+2l}
// (mask/target range) and {256+2l,257+2l,384+2l,385+2l} (pick-only).
// No __syncthreads in the row loop; all row reductions are wave-local.
__global__ __launch_bounds__(256, 6) void setcrit_stage1(
    const float* __restrict__ pred_class,
    const float* __restrict__ pred_v,
    const float* __restrict__ targets,
    float* __restrict__ partial)
{
    __shared__ float s_predv[4][N_DIM];   // private slice per wave
    __shared__ float s_fin[4][4];

    const int tid = threadIdx.x;
    const int l   = tid & 63;
    const int w   = tid >> 6;
    const unsigned long long lt = (1ull << l) - 1ull;
    const int wave_id = blockIdx.x * 4 + w;   // 8192 waves, 2 rows each

    float acc_pick = 0.f, acc_dsq = 0.f, acc_multi = 0.f;
    int   acc_tc = 0;

#pragma unroll
    for (int i = 0; i < 2; ++i) {
        const int b = i * (NBLK * 4) + wave_id;
        const float* lgp = pred_class + (size_t)b * (2 * F_DIM);
        const float* pvp = pred_v     + (size_t)b * N_DIM;
        const float* tgp = targets    + (size_t)b * T_DIM;

        // ---- issue all row loads up front (coalesced, independent) ----
        float4 g0 = *(const float4*)(lgp + 4 * l);         // f = 2l, 2l+1
        float4 g1 = *(const float4*)(lgp + 256 + 4 * l);   // f = 128+2l, 129+2l
        float4 g2 = *(const float4*)(lgp + 512 + 4 * l);   // f = 256+2l, 257+2l
        float4 g3 = *(const float4*)(lgp + 768 + 4 * l);   // f = 384+2l, 385+2l
        float4 pv = *(const float4*)(pvp + 4 * l);         // n = 4l..4l+3
        float2 t0 = *(const float2*)(tgp + 2 * l);         // t = 2l, 2l+1
        float2 t1 = *(const float2*)(tgp + 128 + 2 * l);   // t = 128+2l, 129+2l

        *(float4*)(&s_predv[w][4 * l]) = pv;               // stage for gather

        // ---- log-softmax picks: f<256 -> logp[1], f>=256 -> logp[0] ----
        float p = 0.f;
        p += g0.y - lse2(g0.x, g0.y);
        p += g0.w - lse2(g0.z, g0.w);
        p += g1.y - lse2(g1.x, g1.y);
        p += g1.w - lse2(g1.z, g1.w);
        p += g2.x - lse2(g2.x, g2.y);
        p += g2.z - lse2(g2.z, g2.w);
        p += g3.x - lse2(g3.x, g3.y);
        p += g3.z - lse2(g3.z, g3.w);
        acc_pick += p;

        // ---- mask + exclusive prefix over t in [0,256) via 4 ballots ----
        bool m0 = g0.y > g0.x;   // t = 2l
        bool m1 = g0.w > g0.z;   // t = 2l+1
        bool m2 = g1.y > g1.x;   // t = 128+2l
        bool m3 = g1.w > g1.z;   // t = 128+2l+1
        unsigned long long b0 = __ballot(m0);
        unsigned long long b1 = __ballot(m1);
        unsigned long long b2 = __ballot(m2);
        unsigned long long b3 = __ballot(m3);

        int c0 = __popcll(b0), c1 = __popcll(b1);
        int c2 = __popcll(b2), c3 = __popcll(b3);
        int e0 = __popcll(b0 & lt) + __popcll(b1 & lt);
        int e1 = e0 + (m0 ? 1 : 0);
        int h  = c0 + c1;
        int e2 = h + __popcll(b2 & lt) + __popcll(b3 & lt);
        int e3 = e2 + (m2 ? 1 : 0);
        acc_tc += h + c2 + c3;

        // ---- matched gather + squared error (tc==0 rows contribute 0) ----
        float dsq = 0.f, d;
        if (m0) { d = s_predv[w][e0] - t0.x; dsq += d * d; }
        if (m1) { d = s_predv[w][e1] - t0.y; dsq += d * d; }
        if (m2) { d = s_predv[w][e2] - t1.x; dsq += d * d; }
        if (m3) { d = s_predv[w][e3] - t1.y; dsq += d * d; }
        acc_dsq += dsq;

        // ---- product over the row (per-row nonlinear term) ----
        float prod = wave_prod(pv.x * pv.y * pv.z * pv.w);
        float pm1 = prod - 1.f;
        acc_multi += pm1 * pm1;
    }

    float pickS = wave_sum(acc_pick);
    float dsqS  = wave_sum(acc_dsq);
    if (l == 0) {
        s_fin[w][0] = pickS;
        s_fin[w][1] = acc_multi;
        s_fin[w][2] = dsqS;
        s_fin[w][3] = (float)acc_tc;
    }
    __syncthreads();
    if (tid == 0) {
        float v0 = 0.f, v1 = 0.f, v2 = 0.f, v3 = 0.f;
#pragma unroll
        for (int k = 0; k < 4; ++k) {
            v0 += s_fin[k][0]; v1 += s_fin[k][1];
            v2 += s_fin[k][2]; v3 += s_fin[k][3];
        }
        partial[0 * NBLK + blockIdx.x] = v0;
        partial[1 * NBLK + blockIdx.x] = v1;
        partial[2 * NBLK + blockIdx.x] = v2 * (1.f / (float)T_DIM);
        partial[3 * NBLK + blockIdx.x] = v3 * (1.f / (float)T_DIM);
    }
}

__global__ __launch_bounds__(256) void setcrit_stage2(
    const float* __restrict__ partial, float* __restrict__ out)
{
    __shared__ float s_red[4];
    const int tid  = threadIdx.x;
    const int lane = tid & 63;
    const int wv   = tid >> 6;
    float sums[4];
#pragma unroll
    for (int k = 0; k < 4; ++k) {
        float v = 0.f;
        for (int i = tid; i < NBLK; i += 256) v += partial[k * NBLK + i];
        v = wave_sum(v);
        if (lane == 0) s_red[wv] = v;
        __syncthreads();
        sums[k] = s_red[0] + s_red[1] + s_red[2] + s_red[3];
        __syncthreads();
    }
    if (tid == 0) {
        float loss_label = -sums[0] / ((float)B_TOT * (float)F_DIM);
        float loss_multi = sums[1] / (float)B_TOT;
        float loss_true  = sums[2] / (float)B_TOT;
        float f1         = sums[3] / (float)B_TOT;
        float r = loss_multi + loss_true;
        out[0] = loss_label + r;
        out[1] = loss_label;
        out[2] = r;
        out[3] = loss_multi;
        out[4] = loss_true;
        out[5] = f1;
    }
}

extern "C" void kernel_launch(void* const* d_in, const int* in_sizes, int n_in,
                              void* d_out, int out_size, void* d_ws, size_t ws_size,
                              hipStream_t stream) {
    const float* pred_class = (const float*)d_in[0];
    const float* pred_v     = (const float*)d_in[1];
    const float* targets    = (const float*)d_in[2];
    float* partial = (float*)d_ws;  // 4 * NBLK floats = 32 KB

    setcrit_stage1<<<NBLK, 256, 0, stream>>>(pred_class, pred_v, targets, partial);
    setcrit_stage2<<<1, 256, 0, stream>>>(partial, (float*)d_out);
}

// Round 3
// 24.405 us; speedup vs baseline: 1.5288x; 1.3078x over previous
//
#include <hip/hip_runtime.h>

#define B_TOT 16384
#define F_DIM 512
#define T_DIM 256
#define N_DIM 256
#define NBLK  2048

__device__ __forceinline__ float wave_sum(float v) {
#pragma unroll
    for (int o = 32; o; o >>= 1) v += __shfl_xor(v, o, 64);
    return v;
}
__device__ __forceinline__ float wave_prod(float v) {
#pragma unroll
    for (int o = 32; o; o >>= 1) v *= __shfl_xor(v, o, 64);
    return v;
}

__device__ __forceinline__ float lse2(float a, float b) {
    float m = fmaxf(a, b);
    return m + __logf(__expf(a - m) + __expf(b - m));
}

// One wave per row, 2 rows per wave. Lane l owns f in {4l..4l+3} (mask/target
// range, t=4l..4l+3 -> one float4 target load) and {256+4l..259+4l} (pick-only).
// No __syncthreads in the row loop; all row reductions are wave-local.
__global__ __launch_bounds__(256, 4) void setcrit_stage1(
    const float* __restrict__ pred_class,
    const float* __restrict__ pred_v,
    const float* __restrict__ targets,
    float* __restrict__ partial)
{
    __shared__ float s_predv[4][N_DIM];   // private slice per wave
    __shared__ float s_fin[4][4];

    const int tid = threadIdx.x;
    const int l   = tid & 63;
    const int w   = tid >> 6;
    const unsigned long long lt = (1ull << l) - 1ull;
    const int wave_id = blockIdx.x * 4 + w;   // 8192 waves, 2 rows each

    float acc_pick = 0.f, acc_dsq = 0.f, acc_multi = 0.f;
    int   acc_tc = 0;

#pragma unroll
    for (int i = 0; i < 2; ++i) {
        const int b = i * (NBLK * 4) + wave_id;
        const float* lgp = pred_class + (size_t)b * (2 * F_DIM);
        const float* pvp = pred_v     + (size_t)b * N_DIM;
        const float* tgp = targets    + (size_t)b * T_DIM;

        // ---- issue all row loads up front (independent) ----
        float4 g0 = *(const float4*)(lgp + 8 * l);          // f = 4l, 4l+1
        float4 g1 = *(const float4*)(lgp + 8 * l + 4);      // f = 4l+2, 4l+3
        float4 g2 = *(const float4*)(lgp + 512 + 8 * l);    // f = 256+4l, 257+4l
        float4 g3 = *(const float4*)(lgp + 512 + 8 * l + 4);// f = 258+4l, 259+4l
        float4 pv = *(const float4*)(pvp + 4 * l);          // n = 4l..4l+3
        float4 tg = *(const float4*)(tgp + 4 * l);          // t = 4l..4l+3

        *(float4*)(&s_predv[w][4 * l]) = pv;                // stage for gather

        // ---- log-softmax picks: f<256 -> logp[1], f>=256 -> logp[0] ----
        float p = 0.f;
        p += g0.y - lse2(g0.x, g0.y);
        p += g0.w - lse2(g0.z, g0.w);
        p += g1.y - lse2(g1.x, g1.y);
        p += g1.w - lse2(g1.z, g1.w);
        p += g2.x - lse2(g2.x, g2.y);
        p += g2.z - lse2(g2.z, g2.w);
        p += g3.x - lse2(g3.x, g3.y);
        p += g3.z - lse2(g3.z, g3.w);
        acc_pick += p;

        // ---- mask + exclusive prefix over t=4l..4l+3 via 4 ballots ----
        bool m0 = g0.y > g0.x;   // t = 4l
        bool m1 = g0.w > g0.z;   // t = 4l+1
        bool m2 = g1.y > g1.x;   // t = 4l+2
        bool m3 = g1.w > g1.z;   // t = 4l+3
        unsigned long long b0 = __ballot(m0);
        unsigned long long b1 = __ballot(m1);
        unsigned long long b2 = __ballot(m2);
        unsigned long long b3 = __ballot(m3);

        int e0 = __popcll(b0 & lt) + __popcll(b1 & lt)
               + __popcll(b2 & lt) + __popcll(b3 & lt);
        int e1 = e0 + (m0 ? 1 : 0);
        int e2 = e1 + (m1 ? 1 : 0);
        int e3 = e2 + (m2 ? 1 : 0);
        acc_tc += __popcll(b0) + __popcll(b1) + __popcll(b2) + __popcll(b3);

        // ---- matched gather + squared error (tc==0 rows contribute 0) ----
        float dsq = 0.f, d;
        if (m0) { d = s_predv[w][e0] - tg.x; dsq += d * d; }
        if (m1) { d = s_predv[w][e1] - tg.y; dsq += d * d; }
        if (m2) { d = s_predv[w][e2] - tg.z; dsq += d * d; }
        if (m3) { d = s_predv[w][e3] - tg.w; dsq += d * d; }
        acc_dsq += dsq;

        // ---- product over the row (per-row nonlinear term) ----
        float prod = wave_prod(pv.x * pv.y * pv.z * pv.w);
        float pm1 = prod - 1.f;
        acc_multi += pm1 * pm1;
    }

    float pickS = wave_sum(acc_pick);
    float dsqS  = wave_sum(acc_dsq);
    if (l == 0) {
        s_fin[w][0] = pickS;
        s_fin[w][1] = acc_multi;
        s_fin[w][2] = dsqS;
        s_fin[w][3] = (float)acc_tc;
    }
    __syncthreads();
    if (tid == 0) {
        float v0 = 0.f, v1 = 0.f, v2 = 0.f, v3 = 0.f;
#pragma unroll
        for (int k = 0; k < 4; ++k) {
            v0 += s_fin[k][0]; v1 += s_fin[k][1];
            v2 += s_fin[k][2]; v3 += s_fin[k][3];
        }
        partial[0 * NBLK + blockIdx.x] = v0;
        partial[1 * NBLK + blockIdx.x] = v1;
        partial[2 * NBLK + blockIdx.x] = v2 * (1.f / (float)T_DIM);
        partial[3 * NBLK + blockIdx.x] = v3 * (1.f / (float)T_DIM);
    }
}

// Wave w reduces component w: 32 independent loads/lane, one shuffle tree,
// one barrier, thread 0 composes the 6 outputs.
__global__ __launch_bounds__(256) void setcrit_stage2(
    const float* __restrict__ partial, float* __restrict__ out)
{
    __shared__ float s_red[4];
    const int tid = threadIdx.x;
    const int l   = tid & 63;
    const int w   = tid >> 6;

    float v = 0.f;
#pragma unroll
    for (int i = 0; i < NBLK / 64; ++i)
        v += partial[w * NBLK + i * 64 + l];
    v = wave_sum(v);
    if (l == 0) s_red[w] = v;
    __syncthreads();

    if (tid == 0) {
        float loss_label = -s_red[0] / ((float)B_TOT * (float)F_DIM);
        float loss_multi = s_red[1] / (float)B_TOT;
        float loss_true  = s_red[2] / (float)B_TOT;
        float f1         = s_red[3] / (float)B_TOT;
        float r = loss_multi + loss_true;
        out[0] = loss_label + r;
        out[1] = loss_label;
        out[2] = r;
        out[3] = loss_multi;
        out[4] = loss_true;
        out[5] = f1;
    }
}

extern "C" void kernel_launch(void* const* d_in, const int* in_sizes, int n_in,
                              void* d_out, int out_size, void* d_ws, size_t ws_size,
                              hipStream_t stream) {
    const float* pred_class = (const float*)d_in[0];
    const float* pred_v     = (const float*)d_in[1];
    const float* targets    = (const float*)d_in[2];
    float* partial = (float*)d_ws;  // 4 * NBLK floats = 32 KB

    setcrit_stage1<<<NBLK, 256, 0, stream>>>(pred_class, pred_v, targets, partial);
    setcrit_stage2<<<1, 256, 0, stream>>>(partial, (float*)d_out);
}